// Round 5
// baseline (2045.253 us; speedup 1.0000x reference)
//
#include <hip/hip_runtime.h>
#include <hip/hip_bf16.h>
#include <math.h>

// B=8 C=32 P=128 D=256 H=8 R=32; time: 256 seqs x 128; chan: 1024 seqs x 32.
// Both paths: 32768 rows x 256. d_out is FP32 (2 x 8,388,608 elements = 67 MB).
// ws (>=166 MiB known from round history): 4 fp32 planes (128 MiB) + stats (6 MiB).
// g1/g2 are bf16-packed in place into the quR plane (block-local regions, ordered
// by __syncthreads; no __restrict__ on the aliased pointers).
#define LOG2T_16 0.8304820237218406f  // log2(10000)/16

__device__ __forceinline__ float bf2f(unsigned short u) {
    union { float f; unsigned int i; } x; x.i = ((unsigned int)u) << 16; return x.f;
}
__device__ __forceinline__ unsigned short f2b(float f) {
    __hip_bfloat16 h = __float2bfloat16(f);
    union { __hip_bfloat16 h; unsigned short u; } x; x.h = h; return x.u;
}
__device__ __forceinline__ unsigned int packbf(float g1, float g2) {
    return (unsigned int)f2b(g1) | ((unsigned int)f2b(g2) << 16);
}
__device__ __forceinline__ float unpk_lo(unsigned int w) {
    union { float f; unsigned int i; } x; x.i = w << 16; return x.f;
}
__device__ __forceinline__ float unpk_hi(unsigned int w) {
    union { float f; unsigned int i; } x; x.i = w & 0xffff0000u; return x.f;
}

__device__ __forceinline__ float v5_dot32(const float* qurow, const float* row) {
    float dot = 0.f;
#pragma unroll
    for (int q = 0; q < 8; q++) {
        float4 x = *(const float4*)(row + q * 4);
        dot = fmaf(qurow[q * 4 + 0], x.x, dot);
        dot = fmaf(qurow[q * 4 + 1], x.y, dot);
        dot = fmaf(qurow[q * 4 + 2], x.z, dot);
        dot = fmaf(qurow[q * 4 + 3], x.w, dot);
    }
    return dot;
}

__device__ __forceinline__ void v5_fma16(float p_, const float* row, int r0, float* acc) {
#pragma unroll
    for (int hh = 0; hh < 2; hh++) {
#pragma unroll
        for (int q = 0; q < 2; q++) {
            float4 x = *(const float4*)(row + r0 + hh * 16 + q * 4);
            float xs[4] = {x.x, x.y, x.z, x.w};
#pragma unroll
            for (int i = 0; i < 4; i++)
                acc[hh * 8 + q * 4 + i] = fmaf(p_, xs[i], acc[hh * 8 + q * 4 + i]);
        }
    }
}

__device__ __forceinline__ void v5_fma32(float p_, const float* row, float* acc) {
#pragma unroll
    for (int q = 0; q < 8; q++) {
        float4 x = *(const float4*)(row + q * 4);
        float xs[4] = {x.x, x.y, x.z, x.w};
#pragma unroll
        for (int i = 0; i < 4; i++)
            acc[q * 4 + i] = fmaf(p_, xs[i], acc[q * 4 + i]);
    }
}

// ---------- K1: [qu_rot | qv_rot] = RoPE(qz @ [u;v]^T), 64x64 tiles ----------
__global__ __launch_bounds__(256) void v5_proj(
    const float* __restrict__ qz, const float* __restrict__ u, const float* __restrict__ v,
    float* __restrict__ qu_rot, float* __restrict__ qv_rot, int chan, int posmask)
{
    __shared__ float As[16][68];
    __shared__ float Bs[16][68];
    __shared__ float Ct[64][68];
    const int row0 = blockIdx.x * 64;
    const int col0 = blockIdx.y * 64;               // 0..511
    const float* Bsrc = (col0 < 256) ? (u + col0 * 256) : (v + (col0 - 256) * 256);
    float* Cout = (col0 < 256) ? qu_rot : qv_rot;
    const int ccol0 = col0 & 255;
    const int tid = threadIdx.x;

    const int am = tid >> 2;
    const int ak = (tid & 3) * 4;
    int arow = row0 + am;
    if (chan) {
        int b = arow >> 12, p = (arow >> 5) & 127, c = arow & 31;
        arow = (b * 32 + c) * 128 + p;
    }
    const float* aptr = qz + (size_t)arow * 256 + ak;
    const float* bptr = Bsrc + (size_t)am * 256 + ak;

    const int tm = tid >> 4, tn = tid & 15;
    float acc[4][4] = {};
    for (int k0 = 0; k0 < 256; k0 += 16) {
        float4 a4 = *(const float4*)(aptr + k0);
        float4 b4 = *(const float4*)(bptr + k0);
        As[ak + 0][am] = a4.x; As[ak + 1][am] = a4.y; As[ak + 2][am] = a4.z; As[ak + 3][am] = a4.w;
        Bs[ak + 0][am] = b4.x; Bs[ak + 1][am] = b4.y; Bs[ak + 2][am] = b4.z; Bs[ak + 3][am] = b4.w;
        __syncthreads();
#pragma unroll
        for (int kk = 0; kk < 16; kk++) {
            float4 av = *(const float4*)&As[kk][tm * 4];
            float4 bv = *(const float4*)&Bs[kk][tn * 4];
            float ar[4] = {av.x, av.y, av.z, av.w};
            float br[4] = {bv.x, bv.y, bv.z, bv.w};
#pragma unroll
            for (int i = 0; i < 4; i++)
#pragma unroll
                for (int j = 0; j < 4; j++)
                    acc[i][j] = fmaf(ar[i], br[j], acc[i][j]);
        }
        __syncthreads();
    }
#pragma unroll
    for (int i = 0; i < 4; i++)
        *(float4*)&Ct[tm * 4 + i][tn * 4] = make_float4(acc[i][0], acc[i][1], acc[i][2], acc[i][3]);
    __syncthreads();
    const int r_local = tid >> 2;
    const int fj = (tid & 3) * 8;
    const int m = row0 + r_local;
    const float pos = (float)(m & posmask);
#pragma unroll
    for (int qq = 0; qq < 2; qq++) {
        int fhp = fj + qq * 4;                      // 0..28 step 4
        int hl = fhp >> 4, j0 = fhp & 15;
        int cl = hl * 32 + j0;
        float4 a4 = *(const float4*)&Ct[r_local][cl];
        float4 b4 = *(const float4*)&Ct[r_local][cl + 16];
        float aa[4] = {a4.x, a4.y, a4.z, a4.w};
        float bb[4] = {b4.x, b4.y, b4.z, b4.w};
        float o1[4], o2[4];
#pragma unroll
        for (int i = 0; i < 4; i++) {
            float ang = pos * exp2f(-(float)(j0 + i) * LOG2T_16);
            float sn, cs;
            sincosf(ang, &sn, &cs);
            o1[i] = aa[i] * cs - bb[i] * sn;        // apply
            o2[i] = bb[i] * cs + aa[i] * sn;
        }
        *(float4*)(Cout + (size_t)m * 256 + ccol0 + cl)      = make_float4(o1[0], o1[1], o1[2], o1[3]);
        *(float4*)(Cout + (size_t)m * 256 + ccol0 + cl + 16) = make_float4(o2[0], o2[1], o2[2], o2[3]);
    }
}

// ---------- K2: time-path partial softmax stats ----------
__global__ __launch_bounds__(256) void v5_stats_t(
    const float* __restrict__ quR, const float* __restrict__ qvR,
    const float* __restrict__ mask, float* __restrict__ omax, float* __restrict__ osum)
{
    __shared__ float Qv[128][36];
    const int bid = blockIdx.x;                 // n*8 + h
    const int n = bid >> 3, h = bid & 7;
    const int b = n >> 5, c = n & 31;
    const int tid = threadIdx.x;
    for (int idx = tid * 4; idx < 4096; idx += 1024) {
        int s = idx >> 5, r = idx & 31;
        *(float4*)&Qv[s][r] = *(const float4*)(qvR + ((size_t)(n * 128 + s)) * 256 + h * 32 + r);
    }
    const int s = tid >> 1, toff = (tid & 1) * 64;
    float qurow[32];
    const float* qptr = quR + ((size_t)(n * 128 + s)) * 256 + h * 32;
#pragma unroll
    for (int q = 0; q < 8; q++) {
        float4 x = *(const float4*)(qptr + q * 4);
        qurow[q * 4 + 0] = x.x; qurow[q * 4 + 1] = x.y; qurow[q * 4 + 2] = x.z; qurow[q * 4 + 3] = x.w;
    }
    __syncthreads();
    const float* mrow = mask + (size_t)n * 16384 + s * 128 + toff;
    float mx = -1e30f, sm = 0.f;
#pragma unroll 4
    for (int t = 0; t < 64; t++) {
        float dot = v5_dot32(qurow, &Qv[toff + t][0]);
        float vv = 256.f * (dot + mrow[t]);
        float nm = fmaxf(mx, vv);
        sm = sm * __expf(mx - nm) + __expf(vv - nm);
        mx = nm;
    }
    float omx = __shfl_xor(mx, 1);
    float osm = __shfl_xor(sm, 1);
    float fm = fmaxf(mx, omx);
    float fs = sm * __expf(mx - fm) + osm * __expf(omx - fm);
    if ((tid & 1) == 0) {
        int idx = ((b * 8 + h) * 32 + c) * 128 + s;
        omax[idx] = fm; osum[idx] = fs;
    }
}

// ---------- K3: chan-path partial softmax stats ----------
__global__ __launch_bounds__(256) void v5_stats_c(
    const float* __restrict__ quR, const float* __restrict__ qvR,
    const float* __restrict__ mask, float* __restrict__ omax, float* __restrict__ osum)
{
    __shared__ float Qv[32][260];
    const int m = blockIdx.x;                   // b*128 + p
    const int b = m >> 7, p = m & 127;
    const int tid = threadIdx.x;
    for (int idx = tid * 4; idx < 8192; idx += 1024) {
        int sc = idx >> 8, dd = idx & 255;
        *(float4*)&Qv[sc][dd] = *(const float4*)(qvR + ((size_t)m * 32 + sc) * 256 + dd);
    }
    const int h = tid >> 5, sc = tid & 31;
    float qurow[32];
    const float* qptr = quR + ((size_t)m * 32 + sc) * 256 + h * 32;
#pragma unroll
    for (int q = 0; q < 8; q++) {
        float4 x = *(const float4*)(qptr + q * 4);
        qurow[q * 4 + 0] = x.x; qurow[q * 4 + 1] = x.y; qurow[q * 4 + 2] = x.z; qurow[q * 4 + 3] = x.w;
    }
    __syncthreads();
    const float* mrow = mask + (size_t)m * 1024 + sc * 32;
    float mx = -1e30f, sm = 0.f;
#pragma unroll 4
    for (int t = 0; t < 32; t++) {
        float dot = v5_dot32(qurow, &Qv[t][h * 32]);
        float vv = 256.f * (dot + mrow[t]);
        float nm = fmaxf(mx, vv);
        sm = sm * __expf(mx - nm) + __expf(vv - nm);
        mx = nm;
    }
    int idx = ((b * 8 + h) * 32 + sc) * 128 + p;
    omax[idx] = mx; osum[idx] = sm;
}

// ---------- K4: merge joint-softmax stats ----------
__global__ __launch_bounds__(256) void v5_merge(
    const float* __restrict__ mt, const float* __restrict__ st,
    const float* __restrict__ mc, const float* __restrict__ sc,
    float* __restrict__ Mo, float* __restrict__ So)
{
    int i = blockIdx.x * 256 + threadIdx.x;
    float a = mt[i], b = mc[i];
    float mx = fmaxf(a, b);
    float s = st[i] * __expf(a - mx) + sc[i] * __expf(b - mx);
    Mo[i] = mx;
    So[i] = 1.f / s;
}

// ---------- K5: time-path G; packs bf16 g1|g2 into the quR plane (gpk aliases quR:
// all quR reads precede gpk writes within the block; regions disjoint across blocks;
// NO __restrict__ on the aliased pointers) ----------
__global__ __launch_bounds__(256) void v5_G_t(
    const float* quR, const float* qvR,
    const float* __restrict__ mask, const float* __restrict__ Mr, const float* __restrict__ Sv,
    unsigned int* gpk)
{
    __shared__ float Qv[128][36];
    __shared__ unsigned short Pm[128][132];
    const int bid = blockIdx.x;
    const int n = bid >> 3, h = bid & 7;
    const int b = n >> 5, c = n & 31;
    const int tid = threadIdx.x;
    for (int idx = tid * 4; idx < 4096; idx += 1024) {
        int s = idx >> 5, r = idx & 31;
        *(float4*)&Qv[s][r] = *(const float4*)(qvR + ((size_t)(n * 128 + s)) * 256 + h * 32 + r);
    }
    const int s = tid >> 1;
    const int half = tid & 1;
    const int toff = half * 64;
    const int r0 = half * 8;
    float qurow[32];
    const float* qptr = quR + ((size_t)(n * 128 + s)) * 256 + h * 32;
#pragma unroll
    for (int q = 0; q < 8; q++) {
        float4 x = *(const float4*)(qptr + q * 4);
        qurow[q * 4 + 0] = x.x; qurow[q * 4 + 1] = x.y; qurow[q * 4 + 2] = x.z; qurow[q * 4 + 3] = x.w;
    }
    __syncthreads();
    const int rowidx = ((b * 8 + h) * 32 + c) * 128 + s;
    const float Mx = Mr[rowidx];
    const float Si = Sv[rowidx];
    const float* mrow = mask + (size_t)n * 16384 + s * 128 + toff;
#pragma unroll 4
    for (int t = 0; t < 64; t++) {
        float dot = v5_dot32(qurow, &Qv[toff + t][0]);
        float pv = __expf(256.f * (dot + mrow[t]) - Mx) * Si;
        Pm[s][toff + t] = f2b(pv);
    }
    __syncthreads();
    // g1[s][r] = sum_t P[s][t] * Qv[t][r]
    float acc[16] = {};
#pragma unroll 8
    for (int t = 0; t < 128; t++) {
        float p_ = bf2f(Pm[s][t]);
        v5_fma16(p_, &Qv[t][0], r0, acc);
    }
    __syncthreads();                              // all g1 Qv reads done
    // restage Qo = R(-2theta)*quR into Qv (last quR reads, before any gpk write)
    for (int idx = tid * 4; idx < 2048; idx += 1024) {
        int row = idx >> 4, j0 = idx & 15;
        const float* base = quR + ((size_t)(n * 128 + row)) * 256 + h * 32;
        float4 a4 = *(const float4*)(base + j0);
        float4 b4 = *(const float4*)(base + j0 + 16);
        float aa[4] = {a4.x, a4.y, a4.z, a4.w};
        float bb[4] = {b4.x, b4.y, b4.z, b4.w};
        float o1[4], o2[4];
#pragma unroll
        for (int i = 0; i < 4; i++) {
            float ang = 2.f * (float)row * exp2f(-(float)(j0 + i) * LOG2T_16);
            float s2, c2;
            sincosf(ang, &s2, &c2);
            o1[i] = aa[i] * c2 + bb[i] * s2;
            o2[i] = bb[i] * c2 - aa[i] * s2;
        }
        *(float4*)&Qv[row][j0]      = make_float4(o1[0], o1[1], o1[2], o1[3]);
        *(float4*)&Qv[row][j0 + 16] = make_float4(o2[0], o2[1], o2[2], o2[3]);
    }
    __syncthreads();
    // g2[s][r] = sum_t P[t][s] * Qo[t][r]
    float acc2[16] = {};
#pragma unroll 8
    for (int t = 0; t < 128; t++) {
        float p_ = bf2f(Pm[t][s]);
        v5_fma16(p_, &Qv[t][0], r0, acc2);
    }
    float cs[8], sn[8];
#pragma unroll
    for (int i = 0; i < 8; i++) {
        float ang = (float)s * exp2f(-(float)(r0 + i) * LOG2T_16);
        sincosf(ang, &sn[i], &cs[i]);
    }
    size_t gb = ((size_t)(n * 128 + s)) * 256 + h * 32;
#pragma unroll
    for (int i = 0; i < 8; i++) {
        float g1a = acc[i] * cs[i] + acc[8 + i] * sn[i];    // apply_o
        float g1b = acc[8 + i] * cs[i] - acc[i] * sn[i];
        float g2a = acc2[i] * cs[i] - acc2[8 + i] * sn[i];  // apply
        float g2b = acc2[8 + i] * cs[i] + acc2[i] * sn[i];
        gpk[gb + r0 + i]      = packbf(g1a, g2a);
        gpk[gb + r0 + i + 16] = packbf(g1b, g2b);
    }
}

// ---------- K6: chan-path G; packs bf16 g1|g2 into the quR plane ----------
__global__ __launch_bounds__(256) void v5_G_c(
    const float* quR, const float* qvR,
    const float* __restrict__ mask, const float* __restrict__ Mr, const float* __restrict__ Sv,
    unsigned int* gpk)
{
    __shared__ float Qv[32][260];
    __shared__ unsigned short Pm[8][32][34];
    const int m = blockIdx.x;                     // b*128 + p
    const int b = m >> 7, p = m & 127;
    const int tid = threadIdx.x;
    for (int idx = tid * 4; idx < 8192; idx += 1024) {
        int sc = idx >> 8, dd = idx & 255;
        *(float4*)&Qv[sc][dd] = *(const float4*)(qvR + ((size_t)m * 32 + sc) * 256 + dd);
    }
    const int h = tid >> 5, sc = tid & 31;
    float qurow[32];
    const float* qptr = quR + ((size_t)m * 32 + sc) * 256 + h * 32;
#pragma unroll
    for (int q = 0; q < 8; q++) {
        float4 x = *(const float4*)(qptr + q * 4);
        qurow[q * 4 + 0] = x.x; qurow[q * 4 + 1] = x.y; qurow[q * 4 + 2] = x.z; qurow[q * 4 + 3] = x.w;
    }
    __syncthreads();
    const int rowidx = ((b * 8 + h) * 32 + sc) * 128 + p;
    const float Mx = Mr[rowidx], Si = Sv[rowidx];
    const float* mrow = mask + (size_t)m * 1024 + sc * 32;
    float pv[32];
#pragma unroll
    for (int t = 0; t < 32; t++) {
        float dot = v5_dot32(qurow, &Qv[t][h * 32]);
        pv[t] = __expf(256.f * (dot + mrow[t]) - Mx) * Si;
        Pm[h][t][sc] = f2b(pv[t]);                // Pm[h][cand][query]
    }
    // g1 from register pv
    float a1[32] = {};
#pragma unroll
    for (int t = 0; t < 32; t++) v5_fma32(pv[t], &Qv[t][h * 32], a1);
    __syncthreads();                              // Pm complete; g1 Qv reads done
    // restage Qo = R(-2theta)*quR into Qv (last quR reads, before gpk writes)
    for (int idx = tid * 4; idx < 4096; idx += 1024) {
        int row = idx >> 7, rem = idx & 127;
        int h2 = rem >> 4, j0 = rem & 15;
        const float* base = quR + ((size_t)m * 32 + row) * 256 + h2 * 32;
        float4 a4 = *(const float4*)(base + j0);
        float4 b4 = *(const float4*)(base + j0 + 16);
        float aa[4] = {a4.x, a4.y, a4.z, a4.w};
        float bb[4] = {b4.x, b4.y, b4.z, b4.w};
        float o1[4], o2[4];
#pragma unroll
        for (int i = 0; i < 4; i++) {
            float ang = 2.f * (float)row * exp2f(-(float)(j0 + i) * LOG2T_16);
            float s2, c2;
            sincosf(ang, &s2, &c2);
            o1[i] = aa[i] * c2 + bb[i] * s2;
            o2[i] = bb[i] * c2 - aa[i] * s2;
        }
        *(float4*)&Qv[row][h2 * 32 + j0]      = make_float4(o1[0], o1[1], o1[2], o1[3]);
        *(float4*)&Qv[row][h2 * 32 + j0 + 16] = make_float4(o2[0], o2[1], o2[2], o2[3]);
    }
    __syncthreads();
    // g2[sc][r] = sum_t P[t][sc]*Qo[t][r];  P[t][sc] = Pm[h][sc][t]
    float a2[32] = {};
#pragma unroll
    for (int t = 0; t < 32; t++) {
        float p_ = bf2f(Pm[h][sc][t]);
        v5_fma32(p_, &Qv[t][h * 32], a2);
    }
    float cs[16], sn[16];
#pragma unroll
    for (int i = 0; i < 16; i++) {
        float ang = (float)sc * exp2f(-(float)i * LOG2T_16);
        sincosf(ang, &sn[i], &cs[i]);
    }
    size_t gb = ((size_t)m * 32 + sc) * 256 + h * 32;
#pragma unroll
    for (int i = 0; i < 16; i++) {
        float g1a = a1[i] * cs[i] + a1[i + 16] * sn[i];     // apply_o
        float g1b = a1[i + 16] * cs[i] - a1[i] * sn[i];
        float g2a = a2[i] * cs[i] - a2[i + 16] * sn[i];     // apply
        float g2b = a2[i + 16] * cs[i] + a2[i] * sn[i];
        gpk[gb + i]      = packbf(g1a, g2a);
        gpk[gb + i + 16] = packbf(g1b, g2b);
    }
}

// ---------- K7: out = g1 @ u + g2 @ v (packed A), FP32 out, optional remap ----------
__global__ __launch_bounds__(256) void v5_outgemm(
    const unsigned int* __restrict__ gpk,
    const float* __restrict__ u, const float* __restrict__ v,
    float* __restrict__ out, int remap)
{
    __shared__ float A1s[16][68];
    __shared__ float A2s[16][68];
    __shared__ float Bu[16][68];
    __shared__ float Bv[16][68];
    const int row0 = blockIdx.x * 64;
    const int col0 = blockIdx.y * 64;
    const int tid = threadIdx.x;
    const int am = tid >> 2, ak = (tid & 3) * 4;
    const int bkk = tid >> 4, bj = (tid & 15) * 4;
    const int tm = tid >> 4, tn = tid & 15;
    float acc[4][4] = {};
    for (int k0 = 0; k0 < 256; k0 += 16) {
        uint4 a4 = *(const uint4*)(gpk + (size_t)(row0 + am) * 256 + k0 + ak);
        float4 bu4 = *(const float4*)(u + (size_t)(k0 + bkk) * 256 + col0 + bj);
        float4 bv4 = *(const float4*)(v + (size_t)(k0 + bkk) * 256 + col0 + bj);
        A1s[ak + 0][am] = unpk_lo(a4.x); A2s[ak + 0][am] = unpk_hi(a4.x);
        A1s[ak + 1][am] = unpk_lo(a4.y); A2s[ak + 1][am] = unpk_hi(a4.y);
        A1s[ak + 2][am] = unpk_lo(a4.z); A2s[ak + 2][am] = unpk_hi(a4.z);
        A1s[ak + 3][am] = unpk_lo(a4.w); A2s[ak + 3][am] = unpk_hi(a4.w);
        *(float4*)&Bu[bkk][bj] = bu4;
        *(float4*)&Bv[bkk][bj] = bv4;
        __syncthreads();
#pragma unroll
        for (int kk = 0; kk < 16; kk++) {
            float4 a1v = *(const float4*)&A1s[kk][tm * 4];
            float4 a2v = *(const float4*)&A2s[kk][tm * 4];
            float4 buv = *(const float4*)&Bu[kk][tn * 4];
            float4 bvv = *(const float4*)&Bv[kk][tn * 4];
            float a1r[4] = {a1v.x, a1v.y, a1v.z, a1v.w};
            float a2r[4] = {a2v.x, a2v.y, a2v.z, a2v.w};
            float bur[4] = {buv.x, buv.y, buv.z, buv.w};
            float bvr[4] = {bvv.x, bvv.y, bvv.z, bvv.w};
#pragma unroll
            for (int i = 0; i < 4; i++)
#pragma unroll
                for (int j = 0; j < 4; j++) {
                    acc[i][j] = fmaf(a1r[i], bur[j], acc[i][j]);
                    acc[i][j] = fmaf(a2r[i], bvr[j], acc[i][j]);
                }
        }
        __syncthreads();
    }
#pragma unroll
    for (int i = 0; i < 4; i++) {
        int mr = row0 + tm * 4 + i;
        int orow = mr;
        if (remap) {                               // m=(b,p,c) -> (b,c,p)
            int bb = mr >> 12, pp = (mr >> 5) & 127, cc = mr & 31;
            orow = (bb << 12) + (cc << 7) + pp;
        }
        *(float4*)(out + (size_t)orow * 256 + col0 + tn * 4) =
            make_float4(acc[i][0], acc[i][1], acc[i][2], acc[i][3]);
    }
}

extern "C" void kernel_launch(void* const* d_in, const int* in_sizes, int n_in,
                              void* d_out, int out_size, void* d_ws, size_t ws_size,
                              hipStream_t stream)
{
    (void)in_sizes; (void)n_in; (void)out_size; (void)ws_size;
    const float* qz     = (const float*)d_in[0];
    const float* mask_t = (const float*)d_in[1];
    const float* mask_c = (const float*)d_in[2];
    const float* u_time = (const float*)d_in[3];
    const float* v_time = (const float*)d_in[4];
    const float* u_chan = (const float*)d_in[5];
    const float* v_chan = (const float*)d_in[6];
    float* out = (float*)d_out;                   // FP32 output (reference dtype)
    float* W = (float*)d_ws;

    // ws layout (floats), total 35,127,296 = 140 MiB (ws >= 166 MiB known):
    float* quR_t = W;                             // 8,388,608 each plane
    float* qvR_t = W + 8388608;
    float* quR_c = W + 16777216;
    float* qvR_c = W + 25165824;
    float* S     = W + 33554432;                  // stats: 6 x 262,144
    float* max_t = S;
    float* sum_t = S + 262144;
    float* max_c = S + 524288;
    float* sum_c = S + 786432;
    float* Mrow  = S + 1048576;
    float* Sinv  = S + 1310720;
    unsigned int* GPt = (unsigned int*)quR_t;     // packed g1|g2 (aliases quR_t)
    unsigned int* GPc = (unsigned int*)quR_c;     // packed g1|g2 (aliases quR_c)

    dim3 blk(256);
    v5_proj<<<dim3(512, 8), blk, 0, stream>>>(qz, u_time, v_time, quR_t, qvR_t, 0, 127);
    v5_proj<<<dim3(512, 8), blk, 0, stream>>>(qz, u_chan, v_chan, quR_c, qvR_c, 1, 31);
    v5_stats_t<<<2048, blk, 0, stream>>>(quR_t, qvR_t, mask_t, max_t, sum_t);
    v5_stats_c<<<1024, blk, 0, stream>>>(quR_c, qvR_c, mask_c, max_c, sum_c);
    v5_merge<<<1024, blk, 0, stream>>>(max_t, sum_t, max_c, sum_c, Mrow, Sinv);
    v5_G_t<<<2048, blk, 0, stream>>>(quR_t, qvR_t, mask_t, Mrow, Sinv, GPt);
    v5_outgemm<<<dim3(512, 4), blk, 0, stream>>>(GPt, u_time, v_time, out, 0);
    v5_G_c<<<1024, blk, 0, stream>>>(quR_c, qvR_c, mask_c, Mrow, Sinv, GPc);
    v5_outgemm<<<dim3(512, 4), blk, 0, stream>>>(GPc, u_chan, v_chan, out + 8388608, 1);
}

// Round 6
// 1054.935 us; speedup vs baseline: 1.9387x; 1.9387x over previous
//
#include <hip/hip_runtime.h>
#include <hip/hip_bf16.h>
#include <math.h>

// B=8 C=32 P=128 D=256 H=8 R=32; time: 256 seqs x 128; chan: 1024 seqs x 32.
// Both paths: 32768 rows x 256. d_out FP32 (2 x 8,388,608). ws >= 166 MiB.
// g1/g2 bf16-packed in place into the quR plane (lo=g1, hi=g2 ushort halves).
#define LOG2T_16 0.8304820237218406f  // log2(10000)/16

__device__ __forceinline__ float bf2f(unsigned short u) {
    union { float f; unsigned int i; } x; x.i = ((unsigned int)u) << 16; return x.f;
}
__device__ __forceinline__ unsigned short f2b(float f) {
    __hip_bfloat16 h = __float2bfloat16(f);
    union { __hip_bfloat16 h; unsigned short u; } x; x.h = h; return x.u;
}
__device__ __forceinline__ float unpk_lo(unsigned int w) {
    union { float f; unsigned int i; } x; x.i = w << 16; return x.f;
}
__device__ __forceinline__ float unpk_hi(unsigned int w) {
    union { float f; unsigned int i; } x; x.i = w & 0xffff0000u; return x.f;
}

__device__ __forceinline__ float v5_dot32(const float* qurow, const float* row) {
    float dot = 0.f;
#pragma unroll
    for (int q = 0; q < 8; q++) {
        float4 x = *(const float4*)(row + q * 4);
        dot = fmaf(qurow[q * 4 + 0], x.x, dot);
        dot = fmaf(qurow[q * 4 + 1], x.y, dot);
        dot = fmaf(qurow[q * 4 + 2], x.z, dot);
        dot = fmaf(qurow[q * 4 + 3], x.w, dot);
    }
    return dot;
}

__device__ __forceinline__ void v5_fma16(float p_, const float* row, int r0, float* acc) {
#pragma unroll
    for (int hh = 0; hh < 2; hh++) {
#pragma unroll
        for (int q = 0; q < 2; q++) {
            float4 x = *(const float4*)(row + r0 + hh * 16 + q * 4);
            float xs[4] = {x.x, x.y, x.z, x.w};
#pragma unroll
            for (int i = 0; i < 4; i++)
                acc[hh * 8 + q * 4 + i] = fmaf(p_, xs[i], acc[hh * 8 + q * 4 + i]);
        }
    }
}

__device__ __forceinline__ void v5_fma32(float p_, const float* row, float* acc) {
#pragma unroll
    for (int q = 0; q < 8; q++) {
        float4 x = *(const float4*)(row + q * 4);
        float xs[4] = {x.x, x.y, x.z, x.w};
#pragma unroll
        for (int i = 0; i < 4; i++)
            acc[q * 4 + i] = fmaf(p_, xs[i], acc[q * 4 + i]);
    }
}

// ---------- K1: [qu_rot | qv_rot] = RoPE(qz @ [u;v]^T), 64x64 tiles (unchanged) ----------
__global__ __launch_bounds__(256) void v5_proj(
    const float* __restrict__ qz, const float* __restrict__ u, const float* __restrict__ v,
    float* __restrict__ qu_rot, float* __restrict__ qv_rot, int chan, int posmask)
{
    __shared__ float As[16][68];
    __shared__ float Bs[16][68];
    __shared__ float Ct[64][68];
    const int row0 = blockIdx.x * 64;
    const int col0 = blockIdx.y * 64;               // 0..511
    const float* Bsrc = (col0 < 256) ? (u + col0 * 256) : (v + (col0 - 256) * 256);
    float* Cout = (col0 < 256) ? qu_rot : qv_rot;
    const int ccol0 = col0 & 255;
    const int tid = threadIdx.x;

    const int am = tid >> 2;
    const int ak = (tid & 3) * 4;
    int arow = row0 + am;
    if (chan) {
        int b = arow >> 12, p = (arow >> 5) & 127, c = arow & 31;
        arow = (b * 32 + c) * 128 + p;
    }
    const float* aptr = qz + (size_t)arow * 256 + ak;
    const float* bptr = Bsrc + (size_t)am * 256 + ak;

    const int tm = tid >> 4, tn = tid & 15;
    float acc[4][4] = {};
    for (int k0 = 0; k0 < 256; k0 += 16) {
        float4 a4 = *(const float4*)(aptr + k0);
        float4 b4 = *(const float4*)(bptr + k0);
        As[ak + 0][am] = a4.x; As[ak + 1][am] = a4.y; As[ak + 2][am] = a4.z; As[ak + 3][am] = a4.w;
        Bs[ak + 0][am] = b4.x; Bs[ak + 1][am] = b4.y; Bs[ak + 2][am] = b4.z; Bs[ak + 3][am] = b4.w;
        __syncthreads();
#pragma unroll
        for (int kk = 0; kk < 16; kk++) {
            float4 av = *(const float4*)&As[kk][tm * 4];
            float4 bv = *(const float4*)&Bs[kk][tn * 4];
            float ar[4] = {av.x, av.y, av.z, av.w};
            float br[4] = {bv.x, bv.y, bv.z, bv.w};
#pragma unroll
            for (int i = 0; i < 4; i++)
#pragma unroll
                for (int j = 0; j < 4; j++)
                    acc[i][j] = fmaf(ar[i], br[j], acc[i][j]);
        }
        __syncthreads();
    }
#pragma unroll
    for (int i = 0; i < 4; i++)
        *(float4*)&Ct[tm * 4 + i][tn * 4] = make_float4(acc[i][0], acc[i][1], acc[i][2], acc[i][3]);
    __syncthreads();
    const int r_local = tid >> 2;
    const int fj = (tid & 3) * 8;
    const int m = row0 + r_local;
    const float pos = (float)(m & posmask);
#pragma unroll
    for (int qq = 0; qq < 2; qq++) {
        int fhp = fj + qq * 4;                      // 0..28 step 4
        int hl = fhp >> 4, j0 = fhp & 15;
        int cl = hl * 32 + j0;
        float4 a4 = *(const float4*)&Ct[r_local][cl];
        float4 b4 = *(const float4*)&Ct[r_local][cl + 16];
        float aa[4] = {a4.x, a4.y, a4.z, a4.w};
        float bb[4] = {b4.x, b4.y, b4.z, b4.w};
        float o1[4], o2[4];
#pragma unroll
        for (int i = 0; i < 4; i++) {
            float ang = pos * exp2f(-(float)(j0 + i) * LOG2T_16);
            float sn, cs;
            sincosf(ang, &sn, &cs);                 // precise: pre-softmax path
            o1[i] = aa[i] * cs - bb[i] * sn;        // apply
            o2[i] = bb[i] * cs + aa[i] * sn;
        }
        *(float4*)(Cout + (size_t)m * 256 + ccol0 + cl)      = make_float4(o1[0], o1[1], o1[2], o1[3]);
        *(float4*)(Cout + (size_t)m * 256 + ccol0 + cl + 16) = make_float4(o2[0], o2[1], o2[2], o2[3]);
    }
}

// ---------- K2: time-path partial softmax stats (unchanged) ----------
__global__ __launch_bounds__(256) void v5_stats_t(
    const float* __restrict__ quR, const float* __restrict__ qvR,
    const float* __restrict__ mask, float* __restrict__ omax, float* __restrict__ osum)
{
    __shared__ float Qv[128][36];
    const int bid = blockIdx.x;                 // n*8 + h
    const int n = bid >> 3, h = bid & 7;
    const int b = n >> 5, c = n & 31;
    const int tid = threadIdx.x;
    for (int idx = tid * 4; idx < 4096; idx += 1024) {
        int s = idx >> 5, r = idx & 31;
        *(float4*)&Qv[s][r] = *(const float4*)(qvR + ((size_t)(n * 128 + s)) * 256 + h * 32 + r);
    }
    const int s = tid >> 1, toff = (tid & 1) * 64;
    float qurow[32];
    const float* qptr = quR + ((size_t)(n * 128 + s)) * 256 + h * 32;
#pragma unroll
    for (int q = 0; q < 8; q++) {
        float4 x = *(const float4*)(qptr + q * 4);
        qurow[q * 4 + 0] = x.x; qurow[q * 4 + 1] = x.y; qurow[q * 4 + 2] = x.z; qurow[q * 4 + 3] = x.w;
    }
    __syncthreads();
    const float* mrow = mask + (size_t)n * 16384 + s * 128 + toff;
    float mx = -1e30f, sm = 0.f;
#pragma unroll 4
    for (int t = 0; t < 64; t++) {
        float dot = v5_dot32(qurow, &Qv[toff + t][0]);
        float vv = 256.f * (dot + mrow[t]);
        float nm = fmaxf(mx, vv);
        sm = sm * __expf(mx - nm) + __expf(vv - nm);
        mx = nm;
    }
    float omx = __shfl_xor(mx, 1);
    float osm = __shfl_xor(sm, 1);
    float fm = fmaxf(mx, omx);
    float fs = sm * __expf(mx - fm) + osm * __expf(omx - fm);
    if ((tid & 1) == 0) {
        int idx = ((b * 8 + h) * 32 + c) * 128 + s;
        omax[idx] = fm; osum[idx] = fs;
    }
}

// ---------- K3: chan-path partial softmax stats (unchanged) ----------
__global__ __launch_bounds__(256) void v5_stats_c(
    const float* __restrict__ quR, const float* __restrict__ qvR,
    const float* __restrict__ mask, float* __restrict__ omax, float* __restrict__ osum)
{
    __shared__ float Qv[32][260];
    const int m = blockIdx.x;                   // b*128 + p
    const int b = m >> 7, p = m & 127;
    const int tid = threadIdx.x;
    for (int idx = tid * 4; idx < 8192; idx += 1024) {
        int sc = idx >> 8, dd = idx & 255;
        *(float4*)&Qv[sc][dd] = *(const float4*)(qvR + ((size_t)m * 32 + sc) * 256 + dd);
    }
    const int h = tid >> 5, sc = tid & 31;
    float qurow[32];
    const float* qptr = quR + ((size_t)m * 32 + sc) * 256 + h * 32;
#pragma unroll
    for (int q = 0; q < 8; q++) {
        float4 x = *(const float4*)(qptr + q * 4);
        qurow[q * 4 + 0] = x.x; qurow[q * 4 + 1] = x.y; qurow[q * 4 + 2] = x.z; qurow[q * 4 + 3] = x.w;
    }
    __syncthreads();
    const float* mrow = mask + (size_t)m * 1024 + sc * 32;
    float mx = -1e30f, sm = 0.f;
#pragma unroll 4
    for (int t = 0; t < 32; t++) {
        float dot = v5_dot32(qurow, &Qv[t][h * 32]);
        float vv = 256.f * (dot + mrow[t]);
        float nm = fmaxf(mx, vv);
        sm = sm * __expf(mx - nm) + __expf(vv - nm);
        mx = nm;
    }
    int idx = ((b * 8 + h) * 32 + sc) * 128 + p;
    omax[idx] = mx; osum[idx] = sm;
}

// ---------- K4: merge joint-softmax stats (unchanged) ----------
__global__ __launch_bounds__(256) void v5_merge(
    const float* __restrict__ mt, const float* __restrict__ st,
    const float* __restrict__ mc, const float* __restrict__ sc,
    float* __restrict__ Mo, float* __restrict__ So)
{
    int i = blockIdx.x * 256 + threadIdx.x;
    float a = mt[i], b = mc[i];
    float mx = fmaxf(a, b);
    float s = st[i] * __expf(a - mx) + sc[i] * __expf(b - mx);
    Mo[i] = mx;
    So[i] = 1.f / s;
}

// ---------- K5 v6: time-path G, register-lean. gpk_h is the ushort view of the
// packed plane aliasing quR (lo=g1, hi=g2). All quR reads precede writes. ----------
__global__ __launch_bounds__(256) void v6_G_t(
    const float* quR, const float* qvR,
    const float* __restrict__ mask, const float* __restrict__ Mr, const float* __restrict__ Sv,
    unsigned short* gpk_h)
{
    __shared__ float Qv[128][36];
    __shared__ unsigned short Pm[128][132];
    const int bid = blockIdx.x;
    const int n = bid >> 3, h = bid & 7;
    const int b = n >> 5, c = n & 31;
    const int tid = threadIdx.x;
    for (int idx = tid * 4; idx < 4096; idx += 1024) {
        int s = idx >> 5, r = idx & 31;
        *(float4*)&Qv[s][r] = *(const float4*)(qvR + ((size_t)(n * 128 + s)) * 256 + h * 32 + r);
    }
    const int s = tid >> 1;
    const int half = tid & 1;
    const int toff = half * 64;
    const int r0 = half * 8;
    {
        float qurow[32];
        const float* qptr = quR + ((size_t)(n * 128 + s)) * 256 + h * 32;
#pragma unroll
        for (int q = 0; q < 8; q++) {
            float4 x = *(const float4*)(qptr + q * 4);
            qurow[q * 4 + 0] = x.x; qurow[q * 4 + 1] = x.y; qurow[q * 4 + 2] = x.z; qurow[q * 4 + 3] = x.w;
        }
        __syncthreads();
        const int rowidx = ((b * 8 + h) * 32 + c) * 128 + s;
        const float Mx = Mr[rowidx];
        const float Si = Sv[rowidx];
        const float* mrow = mask + (size_t)n * 16384 + s * 128 + toff;
#pragma unroll 4
        for (int t = 0; t < 64; t++) {
            float dot = v5_dot32(qurow, &Qv[toff + t][0]);
            float pv = __expf(256.f * (dot + mrow[t]) - Mx) * Si;
            Pm[s][toff + t] = f2b(pv);
        }
    }
    __syncthreads();
    // g1[s][r] = sum_t P[s][t] * Qv[t][r]
    float acc[16] = {};
#pragma unroll 8
    for (int t = 0; t < 128; t++) {
        float p_ = bf2f(Pm[s][t]);
        v5_fma16(p_, &Qv[t][0], r0, acc);
    }
    __syncthreads();                              // all g1 Qv reads done
    // restage Qo = R(-2theta)*quR into Qv (LAST quR reads, before any gpk write)
    for (int idx = tid * 4; idx < 2048; idx += 1024) {
        int row = idx >> 4, j0 = idx & 15;
        const float* base = quR + ((size_t)(n * 128 + row)) * 256 + h * 32;
        float4 a4 = *(const float4*)(base + j0);
        float4 b4 = *(const float4*)(base + j0 + 16);
        float aa[4] = {a4.x, a4.y, a4.z, a4.w};
        float bb[4] = {b4.x, b4.y, b4.z, b4.w};
        float o1[4], o2[4];
#pragma unroll
        for (int i = 0; i < 4; i++) {
            float ang = 2.f * (float)row * exp2f(-(float)(j0 + i) * LOG2T_16);
            float s2, c2;
            __sincosf(ang, &s2, &c2);             // fast: post-softmax path
            o1[i] = aa[i] * c2 + bb[i] * s2;
            o2[i] = bb[i] * c2 - aa[i] * s2;
        }
        *(float4*)&Qv[row][j0]      = make_float4(o1[0], o1[1], o1[2], o1[3]);
        *(float4*)&Qv[row][j0 + 16] = make_float4(o2[0], o2[1], o2[2], o2[3]);
    }
    __syncthreads();
    float cs[8], sn[8];
#pragma unroll
    for (int i = 0; i < 8; i++) {
        float ang = (float)s * exp2f(-(float)(r0 + i) * LOG2T_16);
        __sincosf(ang, &sn[i], &cs[i]);
    }
    const size_t gbh = (((size_t)(n * 128 + s)) * 256 + h * 32) * 2;  // ushort index
    // write g1 (lo halves): apply_o, pos = s   — frees acc for reuse
#pragma unroll
    for (int i = 0; i < 8; i++) {
        float x = acc[i], y = acc[8 + i];
        gpk_h[gbh + (r0 + i) * 2]      = f2b(x * cs[i] + y * sn[i]);
        gpk_h[gbh + (r0 + i + 16) * 2] = f2b(y * cs[i] - x * sn[i]);
    }
    // g2[s][r] = sum_t P[t][s] * Qo[t][r] — reuse acc
#pragma unroll
    for (int i = 0; i < 16; i++) acc[i] = 0.f;
#pragma unroll 8
    for (int t = 0; t < 128; t++) {
        float p_ = bf2f(Pm[t][s]);
        v5_fma16(p_, &Qv[t][0], r0, acc);
    }
#pragma unroll
    for (int i = 0; i < 8; i++) {                 // apply, pos = s (hi halves)
        float x = acc[i], y = acc[8 + i];
        gpk_h[gbh + (r0 + i) * 2 + 1]      = f2b(x * cs[i] - y * sn[i]);
        gpk_h[gbh + (r0 + i + 16) * 2 + 1] = f2b(y * cs[i] + x * sn[i]);
    }
}

// ---------- K6 v6: chan-path G, register-lean (the round-5 spill pathology fix) ----------
__global__ __launch_bounds__(256) void v6_G_c(
    const float* quR, const float* qvR,
    const float* __restrict__ mask, const float* __restrict__ Mr, const float* __restrict__ Sv,
    unsigned short* gpk_h)
{
    __shared__ float Qv[32][260];
    __shared__ unsigned short Pm[8][32][34];      // [h][cand][query]
    const int m = blockIdx.x;                     // b*128 + p
    const int b = m >> 7, p = m & 127;
    const int tid = threadIdx.x;
    for (int idx = tid * 4; idx < 8192; idx += 1024) {
        int sc = idx >> 8, dd = idx & 255;
        *(float4*)&Qv[sc][dd] = *(const float4*)(qvR + ((size_t)m * 32 + sc) * 256 + dd);
    }
    const int h = tid >> 5, sc = tid & 31;
    {
        float qurow[32];
        const float* qptr = quR + ((size_t)m * 32 + sc) * 256 + h * 32;
#pragma unroll
        for (int q = 0; q < 8; q++) {
            float4 x = *(const float4*)(qptr + q * 4);
            qurow[q * 4 + 0] = x.x; qurow[q * 4 + 1] = x.y; qurow[q * 4 + 2] = x.z; qurow[q * 4 + 3] = x.w;
        }
        __syncthreads();
        const int rowidx = ((b * 8 + h) * 32 + sc) * 128 + p;
        const float Mx = Mr[rowidx], Si = Sv[rowidx];
        const float* mrow = mask + (size_t)m * 1024 + sc * 32;
#pragma unroll 4
        for (int t = 0; t < 32; t++) {
            float dot = v5_dot32(qurow, &Qv[t][h * 32]);
            float pv = __expf(256.f * (dot + mrow[t]) - Mx) * Si;
            Pm[h][t][sc] = f2b(pv);               // no pv[32] register array
        }
    }
    __syncthreads();                              // Pm complete
    // g1[sc][r] = sum_t P[sc][t] * Qv[t][r]  (P re-read from LDS: own writes)
    float a[32] = {};
#pragma unroll 4
    for (int t = 0; t < 32; t++) {
        float p_ = bf2f(Pm[h][t][sc]);
        v5_fma32(p_, &Qv[t][h * 32], a);
    }
    __syncthreads();                              // g1 Qv reads done
    // restage Qo = R(-2theta)*quR into Qv (LAST quR reads, before gpk writes)
    for (int idx = tid * 4; idx < 4096; idx += 1024) {
        int row = idx >> 7, rem = idx & 127;
        int h2 = rem >> 4, j0 = rem & 15;
        const float* base = quR + ((size_t)m * 32 + row) * 256 + h2 * 32;
        float4 a4 = *(const float4*)(base + j0);
        float4 b4 = *(const float4*)(base + j0 + 16);
        float aa[4] = {a4.x, a4.y, a4.z, a4.w};
        float bb[4] = {b4.x, b4.y, b4.z, b4.w};
        float o1[4], o2[4];
#pragma unroll
        for (int i = 0; i < 4; i++) {
            float ang = 2.f * (float)row * exp2f(-(float)(j0 + i) * LOG2T_16);
            float s2, c2;
            __sincosf(ang, &s2, &c2);             // fast: post-softmax path
            o1[i] = aa[i] * c2 + bb[i] * s2;
            o2[i] = bb[i] * c2 - aa[i] * s2;
        }
        *(float4*)&Qv[row][h2 * 32 + j0]      = make_float4(o1[0], o1[1], o1[2], o1[3]);
        *(float4*)&Qv[row][h2 * 32 + j0 + 16] = make_float4(o2[0], o2[1], o2[2], o2[3]);
    }
    __syncthreads();
    float cs[16], sn[16];
#pragma unroll
    for (int i = 0; i < 16; i++) {
        float ang = (float)sc * exp2f(-(float)i * LOG2T_16);
        __sincosf(ang, &sn[i], &cs[i]);
    }
    const size_t gbh = (((size_t)m * 32 + sc) * 256 + h * 32) * 2;    // ushort index
    // write g1 (lo halves): apply_o, pos = sc — frees a for reuse
#pragma unroll
    for (int i = 0; i < 16; i++) {
        float x = a[i], y = a[i + 16];
        gpk_h[gbh + i * 2]        = f2b(x * cs[i] + y * sn[i]);
        gpk_h[gbh + (i + 16) * 2] = f2b(y * cs[i] - x * sn[i]);
    }
    // g2[sc][r] = sum_t P[t][sc] * Qo[t][r];  P[t][sc] = Pm[h][sc][t] — reuse a
#pragma unroll
    for (int i = 0; i < 32; i++) a[i] = 0.f;
#pragma unroll 4
    for (int t = 0; t < 32; t++) {
        float p_ = bf2f(Pm[h][sc][t]);
        v5_fma32(p_, &Qv[t][h * 32], a);
    }
#pragma unroll
    for (int i = 0; i < 16; i++) {                // apply, pos = sc (hi halves)
        float x = a[i], y = a[i + 16];
        gpk_h[gbh + i * 2 + 1]        = f2b(x * cs[i] - y * sn[i]);
        gpk_h[gbh + (i + 16) * 2 + 1] = f2b(y * cs[i] + x * sn[i]);
    }
}

// ---------- K7: out = g1 @ u + g2 @ v (packed A), FP32 out, optional remap (unchanged) ----------
__global__ __launch_bounds__(256) void v5_outgemm(
    const unsigned int* __restrict__ gpk,
    const float* __restrict__ u, const float* __restrict__ v,
    float* __restrict__ out, int remap)
{
    __shared__ float A1s[16][68];
    __shared__ float A2s[16][68];
    __shared__ float Bu[16][68];
    __shared__ float Bv[16][68];
    const int row0 = blockIdx.x * 64;
    const int col0 = blockIdx.y * 64;
    const int tid = threadIdx.x;
    const int am = tid >> 2, ak = (tid & 3) * 4;
    const int bkk = tid >> 4, bj = (tid & 15) * 4;
    const int tm = tid >> 4, tn = tid & 15;
    float acc[4][4] = {};
    for (int k0 = 0; k0 < 256; k0 += 16) {
        uint4 a4 = *(const uint4*)(gpk + (size_t)(row0 + am) * 256 + k0 + ak);
        float4 bu4 = *(const float4*)(u + (size_t)(k0 + bkk) * 256 + col0 + bj);
        float4 bv4 = *(const float4*)(v + (size_t)(k0 + bkk) * 256 + col0 + bj);
        A1s[ak + 0][am] = unpk_lo(a4.x); A2s[ak + 0][am] = unpk_hi(a4.x);
        A1s[ak + 1][am] = unpk_lo(a4.y); A2s[ak + 1][am] = unpk_hi(a4.y);
        A1s[ak + 2][am] = unpk_lo(a4.z); A2s[ak + 2][am] = unpk_hi(a4.z);
        A1s[ak + 3][am] = unpk_lo(a4.w); A2s[ak + 3][am] = unpk_hi(a4.w);
        *(float4*)&Bu[bkk][bj] = bu4;
        *(float4*)&Bv[bkk][bj] = bv4;
        __syncthreads();
#pragma unroll
        for (int kk = 0; kk < 16; kk++) {
            float4 a1v = *(const float4*)&A1s[kk][tm * 4];
            float4 a2v = *(const float4*)&A2s[kk][tm * 4];
            float4 buv = *(const float4*)&Bu[kk][tn * 4];
            float4 bvv = *(const float4*)&Bv[kk][tn * 4];
            float a1r[4] = {a1v.x, a1v.y, a1v.z, a1v.w};
            float a2r[4] = {a2v.x, a2v.y, a2v.z, a2v.w};
            float bur[4] = {buv.x, buv.y, buv.z, buv.w};
            float bvr[4] = {bvv.x, bvv.y, bvv.z, bvv.w};
#pragma unroll
            for (int i = 0; i < 4; i++)
#pragma unroll
                for (int j = 0; j < 4; j++) {
                    acc[i][j] = fmaf(a1r[i], bur[j], acc[i][j]);
                    acc[i][j] = fmaf(a2r[i], bvr[j], acc[i][j]);
                }
        }
        __syncthreads();
    }
#pragma unroll
    for (int i = 0; i < 4; i++) {
        int mr = row0 + tm * 4 + i;
        int orow = mr;
        if (remap) {                               // m=(b,p,c) -> (b,c,p)
            int bb = mr >> 12, pp = (mr >> 5) & 127, cc = mr & 31;
            orow = (bb << 12) + (cc << 7) + pp;
        }
        *(float4*)(out + (size_t)orow * 256 + col0 + tn * 4) =
            make_float4(acc[i][0], acc[i][1], acc[i][2], acc[i][3]);
    }
}

extern "C" void kernel_launch(void* const* d_in, const int* in_sizes, int n_in,
                              void* d_out, int out_size, void* d_ws, size_t ws_size,
                              hipStream_t stream)
{
    (void)in_sizes; (void)n_in; (void)out_size; (void)ws_size;
    const float* qz     = (const float*)d_in[0];
    const float* mask_t = (const float*)d_in[1];
    const float* mask_c = (const float*)d_in[2];
    const float* u_time = (const float*)d_in[3];
    const float* v_time = (const float*)d_in[4];
    const float* u_chan = (const float*)d_in[5];
    const float* v_chan = (const float*)d_in[6];
    float* out = (float*)d_out;                   // FP32 output (reference dtype)
    float* W = (float*)d_ws;

    // ws layout (floats), total 35,127,296 = 140 MiB:
    float* quR_t = W;                             // 8,388,608 each plane
    float* qvR_t = W + 8388608;
    float* quR_c = W + 16777216;
    float* qvR_c = W + 25165824;
    float* S     = W + 33554432;                  // stats: 6 x 262,144
    float* max_t = S;
    float* sum_t = S + 262144;
    float* max_c = S + 524288;
    float* sum_c = S + 786432;
    float* Mrow  = S + 1048576;
    float* Sinv  = S + 1310720;
    unsigned short* GPt_h = (unsigned short*)quR_t;  // packed g1|g2 ushort view
    unsigned short* GPc_h = (unsigned short*)quR_c;
    unsigned int* GPt = (unsigned int*)quR_t;
    unsigned int* GPc = (unsigned int*)quR_c;

    dim3 blk(256);
    v5_proj<<<dim3(512, 8), blk, 0, stream>>>(qz, u_time, v_time, quR_t, qvR_t, 0, 127);
    v5_proj<<<dim3(512, 8), blk, 0, stream>>>(qz, u_chan, v_chan, quR_c, qvR_c, 1, 31);
    v5_stats_t<<<2048, blk, 0, stream>>>(quR_t, qvR_t, mask_t, max_t, sum_t);
    v5_stats_c<<<1024, blk, 0, stream>>>(quR_c, qvR_c, mask_c, max_c, sum_c);
    v5_merge<<<1024, blk, 0, stream>>>(max_t, sum_t, max_c, sum_c, Mrow, Sinv);
    v6_G_t<<<2048, blk, 0, stream>>>(quR_t, qvR_t, mask_t, Mrow, Sinv, GPt_h);
    v5_outgemm<<<dim3(512, 4), blk, 0, stream>>>(GPt, u_time, v_time, out, 0);
    v6_G_c<<<1024, blk, 0, stream>>>(quR_c, qvR_c, mask_c, Mrow, Sinv, GPc_h);
    v5_outgemm<<<dim3(512, 4), blk, 0, stream>>>(GPc, u_chan, v_chan, out + 8388608, 1);
}